// Round 1
// baseline (1343.756 us; speedup 1.0000x reference)
//
#include <hip/hip_runtime.h>

// Problem constants
namespace {
constexpr int kB  = 2;
constexpr int kL  = 2048;
constexpr int kD  = 1024;
constexpr int kH  = 16;
constexpr int kHD = 64;
constexpr int kM  = kB * kL;      // 4096 total rows
constexpr float kScale = 0.125f;  // 1/sqrt(64)
}

// ---------------------------------------------------------------------------
// GEMM + bias: C = A(M x D) @ W(D x D) + bias
// OUT_HEADS==1: scatter C into (B, H, L, HD) layout; else plain row-major MxD.
// 128x128 block tile, 256 threads, 8x8 per thread (rows {ty*4, 64+ty*4},
// cols {tx*4, 64+tx*4} to keep LDS b128 reads at <=2-way bank aliasing).
// ---------------------------------------------------------------------------
template <int OUT_HEADS>
__global__ __launch_bounds__(256) void gemm_bias_kernel(
    const float* __restrict__ A, const float* __restrict__ W,
    const float* __restrict__ bias, float* __restrict__ C)
{
    __shared__ __align__(16) float As[16][132];  // transposed: As[k][row]
    __shared__ __align__(16) float Bs[16][132];  // Bs[k][col]

    const int tid = threadIdx.x;
    const int tx = tid & 15;
    const int ty = tid >> 4;
    const int br = blockIdx.y * 128;
    const int bc = blockIdx.x * 128;

    float acc[8][8];
#pragma unroll
    for (int i = 0; i < 8; ++i)
#pragma unroll
        for (int j = 0; j < 8; ++j) acc[i][j] = 0.f;

    // global->LDS staging indices
    const int arow = tid >> 2;          // 0..63
    const int ak   = (tid & 3) << 2;    // 0,4,8,12
    const int bk   = tid >> 5;          // 0..7
    const int bj   = (tid & 31) << 2;   // 0..124

    const float* Aptr0 = A + (size_t)(br + arow) * kD + ak;
    const float* Aptr1 = Aptr0 + (size_t)64 * kD;
    const float* Wptr0 = W + (size_t)bk * kD + bc + bj;
    const float* Wptr1 = Wptr0 + (size_t)8 * kD;

    for (int k0 = 0; k0 < kD; k0 += 16) {
        const float4 av0 = *(const float4*)(Aptr0 + k0);
        const float4 av1 = *(const float4*)(Aptr1 + k0);
        const float4 bv0 = *(const float4*)(Wptr0 + (size_t)k0 * kD);
        const float4 bv1 = *(const float4*)(Wptr1 + (size_t)k0 * kD);
        __syncthreads();  // previous compute done before LDS overwrite
        As[ak + 0][arow] = av0.x;
        As[ak + 1][arow] = av0.y;
        As[ak + 2][arow] = av0.z;
        As[ak + 3][arow] = av0.w;
        As[ak + 0][arow + 64] = av1.x;
        As[ak + 1][arow + 64] = av1.y;
        As[ak + 2][arow + 64] = av1.z;
        As[ak + 3][arow + 64] = av1.w;
        *(float4*)&Bs[bk][bj]     = bv0;
        *(float4*)&Bs[bk + 8][bj] = bv1;
        __syncthreads();
#pragma unroll
        for (int k = 0; k < 16; ++k) {
            float a[8], b[8];
            *(float4*)&a[0] = *(const float4*)&As[k][ty * 4];
            *(float4*)&a[4] = *(const float4*)&As[k][64 + ty * 4];
            *(float4*)&b[0] = *(const float4*)&Bs[k][tx * 4];
            *(float4*)&b[4] = *(const float4*)&Bs[k][64 + tx * 4];
#pragma unroll
            for (int i = 0; i < 8; ++i)
#pragma unroll
                for (int j = 0; j < 8; ++j)
                    acc[i][j] = fmaf(a[i], b[j], acc[i][j]);
        }
    }

    float bias0[4], bias1[4];
    *(float4*)bias0 = *(const float4*)&bias[bc + tx * 4];
    *(float4*)bias1 = *(const float4*)&bias[bc + 64 + tx * 4];

#pragma unroll
    for (int i = 0; i < 8; ++i) {
        const int row = br + ((i >> 2) << 6) + ty * 4 + (i & 3);
        float4 r0, r1;
        r0.x = acc[i][0] + bias0[0];
        r0.y = acc[i][1] + bias0[1];
        r0.z = acc[i][2] + bias0[2];
        r0.w = acc[i][3] + bias0[3];
        r1.x = acc[i][4] + bias1[0];
        r1.y = acc[i][5] + bias1[1];
        r1.z = acc[i][6] + bias1[2];
        r1.w = acc[i][7] + bias1[3];
        if (OUT_HEADS) {
            const int b_ = row >> 11;          // row / L
            const int l_ = row & (kL - 1);
            const int j0 = bc + tx * 4;
            const int j1 = j0 + 64;
            float* d0 = C + ((size_t)(b_ * kH + (j0 >> 6)) * kL + l_) * kHD + (j0 & 63);
            float* d1 = C + ((size_t)(b_ * kH + (j1 >> 6)) * kL + l_) * kHD + (j1 & 63);
            *(float4*)d0 = r0;
            *(float4*)d1 = r1;
        } else {
            float* d0 = C + (size_t)row * kD + bc + tx * 4;
            *(float4*)d0 = r0;
            *(float4*)(d0 + 64) = r1;
        }
    }
}

// ---------------------------------------------------------------------------
// Flash attention, fp32. One block = one (b*H+h, 64-row Q tile).
// K/V tiles of 64 staged in LDS (K transposed -> conflict-free b128 reads).
// Online softmax with 16-lane shfl_xor row reductions.
// Writes O directly in (B, L, D) layout for the output projection.
// ---------------------------------------------------------------------------
__global__ __launch_bounds__(256) void attn_kernel(
    const float* __restrict__ Qh, const float* __restrict__ Kh,
    const float* __restrict__ Vh, float* __restrict__ O2)
{
    __shared__ __align__(16) float Qs[64][68];
    __shared__ __align__(16) float Kst[64][68];  // [d][j] (transposed)
    __shared__ __align__(16) float Vs[64][68];   // [j][d]
    __shared__ __align__(16) float Ps[64][68];

    const int tid = threadIdx.x;
    const int tx = tid & 15;
    const int ty = tid >> 4;
    const int qt = blockIdx.x;   // Q tile index (0..31)
    const int bh = blockIdx.y;   // b*H + h (0..31)

    const size_t base = (size_t)bh * kL * kHD;
    const float* Qb = Qh + base;
    const float* Kb = Kh + base;
    const float* Vb = Vh + base;

    // Load Q tile (64 x 64)
#pragma unroll
    for (int i = 0; i < 4; ++i) {
        const int r = i * 16 + ty;
        *(float4*)&Qs[r][tx * 4] =
            *(const float4*)&Qb[(size_t)(qt * 64 + r) * kHD + tx * 4];
    }

    float m[4], lsum[4], o[4][4];
#pragma unroll
    for (int i = 0; i < 4; ++i) {
        m[i] = -__builtin_inff();
        lsum[i] = 0.f;
#pragma unroll
        for (int j = 0; j < 4; ++j) o[i][j] = 0.f;
    }

    for (int kt = 0; kt < kL / 64; ++kt) {
        float4 kreg[4], vreg[4];
#pragma unroll
        for (int i = 0; i < 4; ++i) {
            const int r = i * 16 + ty;
            kreg[i] = *(const float4*)&Kb[(size_t)(kt * 64 + r) * kHD + tx * 4];
            vreg[i] = *(const float4*)&Vb[(size_t)(kt * 64 + r) * kHD + tx * 4];
        }
        __syncthreads();  // previous PV reads done (also covers Q-tile on iter 0)
#pragma unroll
        for (int i = 0; i < 4; ++i) {
            const int r = i * 16 + ty;
            Kst[tx * 4 + 0][r] = kreg[i].x;
            Kst[tx * 4 + 1][r] = kreg[i].y;
            Kst[tx * 4 + 2][r] = kreg[i].z;
            Kst[tx * 4 + 3][r] = kreg[i].w;
            *(float4*)&Vs[r][tx * 4] = vreg[i];
        }
        __syncthreads();

        // S = Q @ K^T for this 64x64 tile; thread owns rows ty*4+., cols tx*4+.
        float s[4][4];
#pragma unroll
        for (int i = 0; i < 4; ++i)
#pragma unroll
            for (int j = 0; j < 4; ++j) s[i][j] = 0.f;

#pragma unroll
        for (int d = 0; d < kHD; d += 4) {
            float qv[4][4], kv[4][4];
#pragma unroll
            for (int ri = 0; ri < 4; ++ri)
                *(float4*)qv[ri] = *(const float4*)&Qs[ty * 4 + ri][d];
#pragma unroll
            for (int dd = 0; dd < 4; ++dd)
                *(float4*)kv[dd] = *(const float4*)&Kst[d + dd][tx * 4];
#pragma unroll
            for (int ri = 0; ri < 4; ++ri)
#pragma unroll
                for (int dd = 0; dd < 4; ++dd)
#pragma unroll
                    for (int cj = 0; cj < 4; ++cj)
                        s[ri][cj] = fmaf(qv[ri][dd], kv[dd][cj], s[ri][cj]);
        }

        // Online softmax update, one row group (16 lanes, same ty) per row
#pragma unroll
        for (int ri = 0; ri < 4; ++ri) {
#pragma unroll
            for (int cj = 0; cj < 4; ++cj) s[ri][cj] *= kScale;
            float tmax = fmaxf(fmaxf(s[ri][0], s[ri][1]), fmaxf(s[ri][2], s[ri][3]));
#pragma unroll
            for (int msk = 1; msk < 16; msk <<= 1)
                tmax = fmaxf(tmax, __shfl_xor(tmax, msk));
            const float mn = fmaxf(m[ri], tmax);
            const float corr = __expf(m[ri] - mn);
            m[ri] = mn;
            float rs = 0.f;
#pragma unroll
            for (int cj = 0; cj < 4; ++cj) {
                const float p = __expf(s[ri][cj] - mn);
                s[ri][cj] = p;
                rs += p;
            }
#pragma unroll
            for (int msk = 1; msk < 16; msk <<= 1) rs += __shfl_xor(rs, msk);
            lsum[ri] = lsum[ri] * corr + rs;
#pragma unroll
            for (int cd = 0; cd < 4; ++cd) o[ri][cd] *= corr;
            *(float4*)&Ps[ty * 4 + ri][tx * 4] =
                make_float4(s[ri][0], s[ri][1], s[ri][2], s[ri][3]);
        }
        __syncthreads();

        // O += P @ V ; thread owns O rows ty*4+., cols (head dims) tx*4+.
#pragma unroll
        for (int j = 0; j < 64; j += 4) {
            float pv[4][4], vv[4][4];
#pragma unroll
            for (int ri = 0; ri < 4; ++ri)
                *(float4*)pv[ri] = *(const float4*)&Ps[ty * 4 + ri][j];
#pragma unroll
            for (int jj = 0; jj < 4; ++jj)
                *(float4*)vv[jj] = *(const float4*)&Vs[j + jj][tx * 4];
#pragma unroll
            for (int ri = 0; ri < 4; ++ri)
#pragma unroll
                for (int jj = 0; jj < 4; ++jj)
#pragma unroll
                    for (int cd = 0; cd < 4; ++cd)
                        o[ri][cd] = fmaf(pv[ri][jj], vv[jj][cd], o[ri][cd]);
        }
    }

    // Epilogue: normalize and write to (B, L, D) layout
    const int b_ = bh >> 4;
    const int h_ = bh & 15;
#pragma unroll
    for (int ri = 0; ri < 4; ++ri) {
        const int row = qt * 64 + ty * 4 + ri;
        const float inv = 1.f / lsum[ri];
        float4 r;
        r.x = o[ri][0] * inv;
        r.y = o[ri][1] * inv;
        r.z = o[ri][2] * inv;
        r.w = o[ri][3] * inv;
        *(float4*)&O2[((size_t)(b_ * kL + row)) * kD + h_ * 64 + tx * 4] = r;
    }
}

// ---------------------------------------------------------------------------
extern "C" void kernel_launch(void* const* d_in, const int* in_sizes, int n_in,
                              void* d_out, int out_size, void* d_ws, size_t ws_size,
                              hipStream_t stream)
{
    const float* q  = (const float*)d_in[0];
    const float* k  = (const float*)d_in[1];
    const float* v  = (const float*)d_in[2];
    const float* Wq = (const float*)d_in[3];
    const float* bq = (const float*)d_in[4];
    const float* Wk = (const float*)d_in[5];
    const float* bk = (const float*)d_in[6];
    const float* Wv = (const float*)d_in[7];
    const float* bv = (const float*)d_in[8];
    const float* Wo = (const float*)d_in[9];
    const float* bo = (const float*)d_in[10];
    float* out = (float*)d_out;

    // Workspace layout: Qh | Kh | Vh (B,H,L,HD each) | O2 (B,L,D)
    float* Qh = (float*)d_ws;
    float* Kh = Qh + (size_t)kM * kD;
    float* Vh = Kh + (size_t)kM * kD;
    float* O2 = Vh + (size_t)kM * kD;

    const dim3 blk(256);
    const dim3 gproj(kD / 128, kM / 128);  // (8, 32)

    hipLaunchKernelGGL((gemm_bias_kernel<1>), gproj, blk, 0, stream, q, Wq, bq, Qh);
    hipLaunchKernelGGL((gemm_bias_kernel<1>), gproj, blk, 0, stream, k, Wk, bk, Kh);
    hipLaunchKernelGGL((gemm_bias_kernel<1>), gproj, blk, 0, stream, v, Wv, bv, Vh);

    hipLaunchKernelGGL(attn_kernel, dim3(kL / 64, kB * kH), blk, 0, stream,
                       Qh, Kh, Vh, O2);

    hipLaunchKernelGGL((gemm_bias_kernel<0>), gproj, blk, 0, stream, O2, Wo, bo, out);
}

// Round 2
// 665.293 us; speedup vs baseline: 2.0198x; 2.0198x over previous
//
#include <hip/hip_runtime.h>

namespace {
constexpr int kB  = 2;
constexpr int kL  = 2048;
constexpr int kD  = 1024;
constexpr int kH  = 16;
constexpr int kHD = 64;
constexpr int kM  = kB * kL;      // 4096 total rows
}

typedef __bf16 bf16x8 __attribute__((ext_vector_type(8)));
typedef float  f32x16 __attribute__((ext_vector_type(16)));

union Frag16 { uint4 u4; unsigned u[4]; bf16x8 v; };

__device__ __forceinline__ unsigned short f2bf(float f) {
    return __builtin_bit_cast(unsigned short, static_cast<__bf16>(f));
}

// ---------------------------------------------------------------------------
// GEMM + bias: C = A(M x D) @ W(D x D) + bias
// MODE 0: fp32 row-major (M x D)            -- final output projection
// MODE 1: bf16 heads layout (B, H, L, HD)   -- Q, K
// MODE 2: bf16 transposed heads (B, H, HD, L) -- V (for direct V^T MFMA frags)
// ---------------------------------------------------------------------------
template <int MODE>
__global__ __launch_bounds__(256) void gemm_bias_kernel(
    const float* __restrict__ A, const float* __restrict__ W,
    const float* __restrict__ bias, void* __restrict__ Cv)
{
    __shared__ __align__(16) float As[16][132];  // transposed: As[k][row]
    __shared__ __align__(16) float Bs[16][132];  // Bs[k][col]

    const int tid = threadIdx.x;
    const int tx = tid & 15;
    const int ty = tid >> 4;
    const int br = blockIdx.y * 128;
    const int bc = blockIdx.x * 128;

    float acc[8][8];
#pragma unroll
    for (int i = 0; i < 8; ++i)
#pragma unroll
        for (int j = 0; j < 8; ++j) acc[i][j] = 0.f;

    const int arow = tid >> 2;          // 0..63
    const int ak   = (tid & 3) << 2;    // 0,4,8,12
    const int bk   = tid >> 5;          // 0..7
    const int bj   = (tid & 31) << 2;   // 0..124

    const float* Aptr0 = A + (size_t)(br + arow) * kD + ak;
    const float* Aptr1 = Aptr0 + (size_t)64 * kD;
    const float* Wptr0 = W + (size_t)bk * kD + bc + bj;
    const float* Wptr1 = Wptr0 + (size_t)8 * kD;

    for (int k0 = 0; k0 < kD; k0 += 16) {
        const float4 av0 = *(const float4*)(Aptr0 + k0);
        const float4 av1 = *(const float4*)(Aptr1 + k0);
        const float4 bv0 = *(const float4*)(Wptr0 + (size_t)k0 * kD);
        const float4 bv1 = *(const float4*)(Wptr1 + (size_t)k0 * kD);
        __syncthreads();
        As[ak + 0][arow] = av0.x;
        As[ak + 1][arow] = av0.y;
        As[ak + 2][arow] = av0.z;
        As[ak + 3][arow] = av0.w;
        As[ak + 0][arow + 64] = av1.x;
        As[ak + 1][arow + 64] = av1.y;
        As[ak + 2][arow + 64] = av1.z;
        As[ak + 3][arow + 64] = av1.w;
        *(float4*)&Bs[bk][bj]     = bv0;
        *(float4*)&Bs[bk + 8][bj] = bv1;
        __syncthreads();
#pragma unroll
        for (int k = 0; k < 16; ++k) {
            float a[8], b[8];
            *(float4*)&a[0] = *(const float4*)&As[k][ty * 4];
            *(float4*)&a[4] = *(const float4*)&As[k][64 + ty * 4];
            *(float4*)&b[0] = *(const float4*)&Bs[k][tx * 4];
            *(float4*)&b[4] = *(const float4*)&Bs[k][64 + tx * 4];
#pragma unroll
            for (int i = 0; i < 8; ++i)
#pragma unroll
                for (int j = 0; j < 8; ++j)
                    acc[i][j] = fmaf(a[i], b[j], acc[i][j]);
        }
    }

    float biasf[8];
    *(float4*)&biasf[0] = *(const float4*)&bias[bc + tx * 4];
    *(float4*)&biasf[4] = *(const float4*)&bias[bc + 64 + tx * 4];

    if (MODE == 2) {
        unsigned short* C = (unsigned short*)Cv;
        const int b_ = br >> 11;
#pragma unroll
        for (int jj = 0; jj < 8; ++jj) {
            const int c = bc + ((jj & 4) << 4) + tx * 4 + (jj & 3);
            const float bb = biasf[jj];
#pragma unroll
            for (int rb = 0; rb < 2; ++rb) {
                const int l0 = (br & (kL - 1)) + rb * 64 + ty * 4;
                ushort4 w;
                w.x = f2bf(acc[rb * 4 + 0][jj] + bb);
                w.y = f2bf(acc[rb * 4 + 1][jj] + bb);
                w.z = f2bf(acc[rb * 4 + 2][jj] + bb);
                w.w = f2bf(acc[rb * 4 + 3][jj] + bb);
                *(ushort4*)&C[((size_t)(b_ * kH + (c >> 6)) * kHD + (c & 63)) * kL + l0] = w;
            }
        }
        return;
    }

#pragma unroll
    for (int i = 0; i < 8; ++i) {
        const int row = br + ((i >> 2) << 6) + ty * 4 + (i & 3);
        float r0[4], r1[4];
#pragma unroll
        for (int j = 0; j < 4; ++j) {
            r0[j] = acc[i][j] + biasf[j];
            r1[j] = acc[i][4 + j] + biasf[4 + j];
        }
        if (MODE == 1) {
            unsigned short* C = (unsigned short*)Cv;
            const int b_ = row >> 11;
            const int l_ = row & (kL - 1);
            const int j0 = bc + tx * 4;
            const int j1 = j0 + 64;
            ushort4 w0 = make_ushort4(f2bf(r0[0]), f2bf(r0[1]), f2bf(r0[2]), f2bf(r0[3]));
            ushort4 w1 = make_ushort4(f2bf(r1[0]), f2bf(r1[1]), f2bf(r1[2]), f2bf(r1[3]));
            *(ushort4*)&C[((size_t)(b_ * kH + (j0 >> 6)) * kL + l_) * kHD + (j0 & 63)] = w0;
            *(ushort4*)&C[((size_t)(b_ * kH + (j1 >> 6)) * kL + l_) * kHD + (j1 & 63)] = w1;
        } else {
            float* C = (float*)Cv;
            float* d0 = C + (size_t)row * kD + bc + tx * 4;
            *(float4*)d0 = make_float4(r0[0], r0[1], r0[2], r0[3]);
            *(float4*)(d0 + 64) = make_float4(r1[0], r1[1], r1[2], r1[3]);
        }
    }
}

// ---------------------------------------------------------------------------
// MFMA flash attention (bf16 inputs, fp32 accum), no LDS.
// One wave owns 32 q rows; block = 4 waves = 128 q rows; grid (16, B*H).
// S^T = mfma(K, Q): C layout -> lane's col = its q row; softmax lane-local
// (16 regs + shfl_xor(32) partner). P^T built in-register (pack + shfl).
// O^T = mfma(V^T, P^T): V stored pre-transposed (B,H,HD,L) by the V-proj.
// ---------------------------------------------------------------------------
__global__ __launch_bounds__(256) void attn_mfma_kernel(
    const unsigned short* __restrict__ Qh, const unsigned short* __restrict__ Kh,
    const unsigned short* __restrict__ Vt, float* __restrict__ O2)
{
    const int lane = threadIdx.x & 63;
    const int wid  = threadIdx.x >> 6;
    const int l31  = lane & 31;
    const int hi   = lane >> 5;
    const int qt = blockIdx.x, bh = blockIdx.y;
    const int q = qt * 128 + wid * 32 + l31;   // this lane's q row

    const size_t qkBase = (size_t)bh * kL * kHD;
    const unsigned short* Qp = Qh + qkBase + (size_t)q * kHD + hi * 8;
    Frag16 qf[4];
#pragma unroll
    for (int d = 0; d < 4; ++d) qf[d].u4 = *(const uint4*)(Qp + d * 16);

    const unsigned short* Kp0 = Kh + qkBase + (size_t)l31 * kHD + hi * 8;
    const unsigned short* Vp0 = Vt + (size_t)bh * kHD * kL + (size_t)l31 * kL + hi * 8;

    f32x16 o0{}, o1{};
    float m = -1e30f, lsum = 0.f;
    const float cexp = 0.125f * 1.44269504089f;  // scale * log2(e)

    for (int kt = 0; kt < kL / 32; ++kt) {
        Frag16 kf[4];
        const unsigned short* kp = Kp0 + (size_t)kt * 32 * kHD;
#pragma unroll
        for (int d = 0; d < 4; ++d) kf[d].u4 = *(const uint4*)(kp + d * 16);

        // V frags: independent of S -> loads overlap the softmax VALU work
        Frag16 vf00, vf01, vf10, vf11;
        vf00.u4 = *(const uint4*)(Vp0 + kt * 32);
        vf01.u4 = *(const uint4*)(Vp0 + kt * 32 + 16);
        vf10.u4 = *(const uint4*)(Vp0 + (size_t)32 * kL + kt * 32);
        vf11.u4 = *(const uint4*)(Vp0 + (size_t)32 * kL + kt * 32 + 16);

        f32x16 c{};
#pragma unroll
        for (int d = 0; d < 4; ++d)
            c = __builtin_amdgcn_mfma_f32_32x32x16_bf16(kf[d].v, qf[d].v, c, 0, 0, 0);

        // ---- online softmax over the 32 new keys (16 in-lane + 16 partner)
        float mx = c[0];
#pragma unroll
        for (int r = 1; r < 16; ++r) mx = fmaxf(mx, c[r]);
        mx = fmaxf(mx, __shfl_xor(mx, 32));
        if (mx > m + 48.f) {               // defer-max: skip rescale when stable
            const float corr = __builtin_amdgcn_exp2f((m - mx) * cexp);
            m = mx;
            lsum *= corr;
            o0 *= corr;
            o1 *= corr;
        }
        const float mc = m * cexp;
        float p[16];
        float rs = 0.f;
#pragma unroll
        for (int r = 0; r < 16; ++r) {
            p[r] = __builtin_amdgcn_exp2f(fmaf(c[r], cexp, -mc));
            rs += p[r];
        }
        rs += __shfl_xor(rs, 32);
        lsum += rs;

        // ---- pack P to bf16 pairs; build P^T B-frags via one partner exchange
        unsigned u[8];
#pragma unroll
        for (int i = 0; i < 8; ++i) {
            union { unsigned short s[2]; unsigned w; } t;
            t.s[0] = f2bf(p[2 * i]);
            t.s[1] = f2bf(p[2 * i + 1]);
            u[i] = t.w;
        }
        unsigned t0 = hi ? u[0] : u[2];
        unsigned t1 = hi ? u[1] : u[3];
        unsigned t2 = hi ? u[4] : u[6];
        unsigned t3 = hi ? u[5] : u[7];
        const unsigned r0 = __shfl_xor(t0, 32);
        const unsigned r1 = __shfl_xor(t1, 32);
        const unsigned r2 = __shfl_xor(t2, 32);
        const unsigned r3 = __shfl_xor(t3, 32);
        Frag16 pf0, pf1;
        pf0.u[0] = hi ? r0 : u[0];
        pf0.u[1] = hi ? r1 : u[1];
        pf0.u[2] = hi ? u[2] : r0;
        pf0.u[3] = hi ? u[3] : r1;
        pf1.u[0] = hi ? r2 : u[4];
        pf1.u[1] = hi ? r3 : u[5];
        pf1.u[2] = hi ? u[6] : r2;
        pf1.u[3] = hi ? u[7] : r3;

        // ---- O^T += V^T @ P^T
        o0 = __builtin_amdgcn_mfma_f32_32x32x16_bf16(vf00.v, pf0.v, o0, 0, 0, 0);
        o0 = __builtin_amdgcn_mfma_f32_32x32x16_bf16(vf01.v, pf1.v, o0, 0, 0, 0);
        o1 = __builtin_amdgcn_mfma_f32_32x32x16_bf16(vf10.v, pf0.v, o1, 0, 0, 0);
        o1 = __builtin_amdgcn_mfma_f32_32x32x16_bf16(vf11.v, pf1.v, o1, 0, 0, 0);
    }

    // ---- epilogue: normalize, write O2 (B, L, D) fp32
    const float inv = 1.f / lsum;
    const int b_ = bh >> 4, h_ = bh & 15;
    float* outp = O2 + ((size_t)(b_ * kL + q)) * kD + h_ * kHD;
#pragma unroll
    for (int g = 0; g < 4; ++g) {
        const int d = g * 8 + hi * 4;
        *(float4*)(outp + d) = make_float4(o0[4 * g + 0] * inv, o0[4 * g + 1] * inv,
                                           o0[4 * g + 2] * inv, o0[4 * g + 3] * inv);
        *(float4*)(outp + 32 + d) = make_float4(o1[4 * g + 0] * inv, o1[4 * g + 1] * inv,
                                                o1[4 * g + 2] * inv, o1[4 * g + 3] * inv);
    }
}

// ---------------------------------------------------------------------------
extern "C" void kernel_launch(void* const* d_in, const int* in_sizes, int n_in,
                              void* d_out, int out_size, void* d_ws, size_t ws_size,
                              hipStream_t stream)
{
    const float* q  = (const float*)d_in[0];
    const float* k  = (const float*)d_in[1];
    const float* v  = (const float*)d_in[2];
    const float* Wq = (const float*)d_in[3];
    const float* bq = (const float*)d_in[4];
    const float* Wk = (const float*)d_in[5];
    const float* bk = (const float*)d_in[6];
    const float* Wv = (const float*)d_in[7];
    const float* bv = (const float*)d_in[8];
    const float* Wo = (const float*)d_in[9];
    const float* bo = (const float*)d_in[10];
    float* out = (float*)d_out;

    // ws: Qh bf16 | Kh bf16 | Vt bf16 (B,H,HD,L) | O2 fp32 (B,L,D)  = 40 MB
    unsigned short* Qh = (unsigned short*)d_ws;
    unsigned short* Kh = Qh + (size_t)kM * kD;
    unsigned short* Vt = Kh + (size_t)kM * kD;
    float* O2 = (float*)(Vt + (size_t)kM * kD);

    const dim3 blk(256);
    const dim3 gproj(kD / 128, kM / 128);  // (8, 32)

    hipLaunchKernelGGL((gemm_bias_kernel<1>), gproj, blk, 0, stream, q, Wq, bq, (void*)Qh);
    hipLaunchKernelGGL((gemm_bias_kernel<1>), gproj, blk, 0, stream, k, Wk, bk, (void*)Kh);
    hipLaunchKernelGGL((gemm_bias_kernel<2>), gproj, blk, 0, stream, v, Wv, bv, (void*)Vt);

    hipLaunchKernelGGL(attn_mfma_kernel, dim3(kL / 128, kB * kH), blk, 0, stream,
                       Qh, Kh, Vt, O2);

    hipLaunchKernelGGL((gemm_bias_kernel<0>), gproj, blk, 0, stream, O2, Wo, bo, (void*)out);
}

// Round 3
// 195.056 us; speedup vs baseline: 6.8891x; 3.4108x over previous
//
#include <hip/hip_runtime.h>

namespace {
constexpr int kB  = 2;
constexpr int kL  = 2048;
constexpr int kD  = 1024;
constexpr int kH  = 16;
constexpr int kHD = 64;
constexpr int kM  = kB * kL;      // 4096 total rows
}

typedef _Float16 f16x8 __attribute__((ext_vector_type(8)));
typedef float    f32x16 __attribute__((ext_vector_type(16)));
typedef unsigned int u32;

union Frag16 { uint4 u4; unsigned u[4]; f16x8 v; };

__device__ __forceinline__ unsigned short f2h(float f) {
    return __builtin_bit_cast(unsigned short, (_Float16)f);
}

// async 16B global -> LDS (wave-uniform LDS base; HW adds lane*16)
__device__ __forceinline__ void gload16(const void* g, void* l) {
    __builtin_amdgcn_global_load_lds(
        (const __attribute__((address_space(1))) u32*)g,
        (__attribute__((address_space(3))) u32*)(unsigned long long)(__builtin_bit_cast(unsigned long long, l)),
        16, 0, 0);
}

// ---------------------------------------------------------------------------
// cast q,k,v (fp32, M x D) -> fp16, same layout. grid (2048, 3)
// ---------------------------------------------------------------------------
__global__ __launch_bounds__(256) void cast_f16_kernel(
    const float* __restrict__ q, const float* __restrict__ k,
    const float* __restrict__ v, unsigned short* __restrict__ dst)
{
    const float* src = blockIdx.y == 0 ? q : (blockIdx.y == 1 ? k : v);
    unsigned short* d = dst + (size_t)blockIdx.y * ((size_t)kM * kD);
    const size_t i = ((size_t)blockIdx.x * 256 + threadIdx.x) * 8;
    const float4 f0 = *(const float4*)(src + i);
    const float4 f1 = *(const float4*)(src + i + 4);
    _Float16 h[8];
    h[0] = (_Float16)f0.x; h[1] = (_Float16)f0.y;
    h[2] = (_Float16)f0.z; h[3] = (_Float16)f0.w;
    h[4] = (_Float16)f1.x; h[5] = (_Float16)f1.y;
    h[6] = (_Float16)f1.z; h[7] = (_Float16)f1.w;
    *(uint4*)(d + i) = *(uint4*)h;
}

// ---------------------------------------------------------------------------
// transpose-cast W (fp32 [k][n]) -> fp16 Wt [n][k]. grid (16, 16, 4)
// ---------------------------------------------------------------------------
__global__ __launch_bounds__(256) void tcast_kernel(
    const float* __restrict__ W0, const float* __restrict__ W1,
    const float* __restrict__ W2, const float* __restrict__ W3,
    unsigned short* __restrict__ WtBase)
{
    __shared__ _Float16 T[64][68];
    const float* W = blockIdx.z == 0 ? W0 : blockIdx.z == 1 ? W1
                   : blockIdx.z == 2 ? W2 : W3;
    unsigned short* Wt = WtBase + (size_t)blockIdx.z * ((size_t)kD * kD);
    const int k0 = blockIdx.y * 64, n0 = blockIdx.x * 64;
    const int tx = threadIdx.x & 15, ty = threadIdx.x >> 4;
#pragma unroll
    for (int i = 0; i < 4; ++i) {
        const int kk = i * 16 + ty;
        const float4 w = *(const float4*)&W[(size_t)(k0 + kk) * kD + n0 + tx * 4];
        T[tx * 4 + 0][kk] = (_Float16)w.x;
        T[tx * 4 + 1][kk] = (_Float16)w.y;
        T[tx * 4 + 2][kk] = (_Float16)w.z;
        T[tx * 4 + 3][kk] = (_Float16)w.w;
    }
    __syncthreads();
#pragma unroll
    for (int i = 0; i < 4; ++i) {
        const int nn = i * 16 + ty;
        *(ushort4*)&Wt[(size_t)(n0 + nn) * kD + k0 + tx * 4] = *(ushort4*)&T[nn][tx * 4];
    }
}

// ---------------------------------------------------------------------------
// fp16 MFMA GEMM + bias: C = A(M x 1024) @ W + bias, W given transposed [n][k].
// 128x128 tile, BK=64, 4 waves x (64x64), mfma_f32_32x32x16_f16.
// global_load_lds staging, pre-swizzled source + XOR-swizzled ds_read (T2).
// LDS double-buffered, one barrier per K-step.
// MODE 0: fp32 row-major; MODE 1: fp16 heads (B,H,L,HD); MODE 2: fp16 (B,H,HD,L)
// grid: 256 blocks flat; by = id&31 (XCD-grouped row panels), bx = id>>5.
// ---------------------------------------------------------------------------
template <int MODE>
__global__ __launch_bounds__(256) void gemm16_kernel(
    const unsigned short* __restrict__ A, const unsigned short* __restrict__ Wt,
    const float* __restrict__ bias, void* __restrict__ Cv)
{
    __shared__ unsigned short Als[2][128 * 64];
    __shared__ unsigned short Bls[2][128 * 64];

    const int tid = threadIdx.x;
    const int lane = tid & 63;
    const int wid = tid >> 6;
    const int l31 = lane & 31;
    const int hi = lane >> 5;
    const int by = blockIdx.x & 31;   // row-panel: same-A blocks share an XCD
    const int bx = blockIdx.x >> 5;
    const int row0 = by * 128;
    const int col0 = bx * 128;
    const int wr = wid >> 1, wc = wid & 1;

    const int rl = lane >> 3;         // row-in-group for staging
    const int sl = lane & 7;          // dest 16B slot
    const int ssrc = (sl ^ rl) * 8;   // swizzled source k-offset (elems)

    const unsigned short* Abase = A + (size_t)(row0 + wid * 32 + rl) * kD + ssrc;
    const unsigned short* Bbase = Wt + (size_t)(col0 + wid * 32 + rl) * kD + ssrc;

    f32x16 acc00{}, acc01{}, acc10{}, acc11{};

    auto stage = [&](int kt, int buf) {
#pragma unroll
        for (int i = 0; i < 4; ++i) {
            gload16(Abase + (size_t)(i * 8) * kD + kt * 64,
                    &Als[buf][(wid * 32 + i * 8) * 64]);
        }
#pragma unroll
        for (int i = 0; i < 4; ++i) {
            gload16(Bbase + (size_t)(i * 8) * kD + kt * 64,
                    &Bls[buf][(wid * 32 + i * 8) * 64]);
        }
    };

    const int ra0 = wr * 64 + l31;          // A rows for this lane
    const int cb0 = wc * 64 + l31;          // B cols for this lane

    stage(0, 0);
    int cur = 0;
    for (int kt = 0; kt < kD / 64; ++kt) {
        __syncthreads();                     // drains vmcnt: buf[cur] ready
        if (kt + 1 < kD / 64) stage(kt + 1, cur ^ 1);
#pragma unroll
        for (int ks = 0; ks < 4; ++ks) {
            const int slot = (ks << 1) | hi;
            Frag16 a0, a1, b0, b1;
            a0.u4 = *(const uint4*)&Als[cur][ra0 * 64 + ((slot ^ (ra0 & 7)) << 3)];
            a1.u4 = *(const uint4*)&Als[cur][(ra0 + 32) * 64 + ((slot ^ ((ra0 + 32) & 7)) << 3)];
            b0.u4 = *(const uint4*)&Bls[cur][cb0 * 64 + ((slot ^ (cb0 & 7)) << 3)];
            b1.u4 = *(const uint4*)&Bls[cur][(cb0 + 32) * 64 + ((slot ^ ((cb0 + 32) & 7)) << 3)];
            acc00 = __builtin_amdgcn_mfma_f32_32x32x16_f16(a0.v, b0.v, acc00, 0, 0, 0);
            acc01 = __builtin_amdgcn_mfma_f32_32x32x16_f16(a0.v, b1.v, acc01, 0, 0, 0);
            acc10 = __builtin_amdgcn_mfma_f32_32x32x16_f16(a1.v, b0.v, acc10, 0, 0, 0);
            acc11 = __builtin_amdgcn_mfma_f32_32x32x16_f16(a1.v, b1.v, acc11, 0, 0, 0);
        }
        cur ^= 1;
    }

    // ---- epilogue ----
    const float bias0 = bias[col0 + wc * 64 + l31];
    const float bias1 = bias[col0 + wc * 64 + 32 + l31];

    const f32x16* accs[2][2] = {{&acc00, &acc01}, {&acc10, &acc11}};
#pragma unroll
    for (int rt = 0; rt < 2; ++rt) {
#pragma unroll
        for (int ct = 0; ct < 2; ++ct) {
            const f32x16& acv = *accs[rt][ct];
            const float bb = ct ? bias1 : bias0;
            const int c = col0 + wc * 64 + ct * 32 + l31;
            if (MODE == 2) {
                // V transposed heads: [b][h][hd][l]; 4 consecutive rows (=l) per quad
                unsigned short* C = (unsigned short*)Cv;
#pragma unroll
                for (int qd = 0; qd < 4; ++qd) {
                    const int r = row0 + wr * 64 + rt * 32 + 8 * qd + 4 * hi;
                    const int b_ = r >> 11, l_ = r & (kL - 1);
                    ushort4 w;
                    w.x = f2h(acv[4 * qd + 0] + bb);
                    w.y = f2h(acv[4 * qd + 1] + bb);
                    w.z = f2h(acv[4 * qd + 2] + bb);
                    w.w = f2h(acv[4 * qd + 3] + bb);
                    *(ushort4*)&C[((size_t)(b_ * kH + (c >> 6)) * kHD + (c & 63)) * kL + l_] = w;
                }
            } else {
#pragma unroll
                for (int reg = 0; reg < 16; ++reg) {
                    const int r = row0 + wr * 64 + rt * 32 + (reg & 3) + 8 * (reg >> 2) + 4 * hi;
                    const float val = acv[reg] + bb;
                    if (MODE == 0) {
                        ((float*)Cv)[(size_t)r * kD + c] = val;
                    } else {
                        const int b_ = r >> 11, l_ = r & (kL - 1);
                        ((unsigned short*)Cv)[((size_t)(b_ * kH + (c >> 6)) * kL + l_) * kHD + (c & 63)] = f2h(val);
                    }
                }
            }
        }
    }
}

// ---------------------------------------------------------------------------
// MFMA flash attention (fp16 inputs, fp32 accum), no LDS.
// S^T = mfma(K, Q); softmax lane-local; O^T = mfma(V^T, P^T); out fp16 (B,L,D).
// ---------------------------------------------------------------------------
__global__ __launch_bounds__(256) void attn_mfma_kernel(
    const unsigned short* __restrict__ Qh, const unsigned short* __restrict__ Kh,
    const unsigned short* __restrict__ Vt, unsigned short* __restrict__ O16)
{
    const int lane = threadIdx.x & 63;
    const int wid  = threadIdx.x >> 6;
    const int l31  = lane & 31;
    const int hi   = lane >> 5;
    const int qt = blockIdx.x, bh = blockIdx.y;
    const int q = qt * 128 + wid * 32 + l31;

    const size_t qkBase = (size_t)bh * kL * kHD;
    const unsigned short* Qp = Qh + qkBase + (size_t)q * kHD + hi * 8;
    Frag16 qf[4];
#pragma unroll
    for (int d = 0; d < 4; ++d) qf[d].u4 = *(const uint4*)(Qp + d * 16);

    const unsigned short* Kp0 = Kh + qkBase + (size_t)l31 * kHD + hi * 8;
    const unsigned short* Vp0 = Vt + (size_t)bh * kHD * kL + (size_t)l31 * kL + hi * 8;

    f32x16 o0{}, o1{};
    float m = -1e30f, lsum = 0.f;
    const float cexp = 0.125f * 1.44269504089f;

    for (int kt = 0; kt < kL / 32; ++kt) {
        Frag16 kf[4];
        const unsigned short* kp = Kp0 + (size_t)kt * 32 * kHD;
#pragma unroll
        for (int d = 0; d < 4; ++d) kf[d].u4 = *(const uint4*)(kp + d * 16);

        Frag16 vf00, vf01, vf10, vf11;
        vf00.u4 = *(const uint4*)(Vp0 + kt * 32);
        vf01.u4 = *(const uint4*)(Vp0 + kt * 32 + 16);
        vf10.u4 = *(const uint4*)(Vp0 + (size_t)32 * kL + kt * 32);
        vf11.u4 = *(const uint4*)(Vp0 + (size_t)32 * kL + kt * 32 + 16);

        f32x16 c{};
#pragma unroll
        for (int d = 0; d < 4; ++d)
            c = __builtin_amdgcn_mfma_f32_32x32x16_f16(kf[d].v, qf[d].v, c, 0, 0, 0);

        float mx = c[0];
#pragma unroll
        for (int r = 1; r < 16; ++r) mx = fmaxf(mx, c[r]);
        mx = fmaxf(mx, __shfl_xor(mx, 32));
        if (mx > m + 48.f) {
            const float corr = __builtin_amdgcn_exp2f((m - mx) * cexp);
            m = mx;
            lsum *= corr;
            o0 *= corr;
            o1 *= corr;
        }
        const float mc = m * cexp;
        float p[16];
        float rs = 0.f;
#pragma unroll
        for (int r = 0; r < 16; ++r) {
            p[r] = __builtin_amdgcn_exp2f(fmaf(c[r], cexp, -mc));
            rs += p[r];
        }
        rs += __shfl_xor(rs, 32);
        lsum += rs;

        unsigned u[8];
#pragma unroll
        for (int i = 0; i < 8; ++i) {
            union { _Float16 h[2]; unsigned w; } t;
            t.h[0] = (_Float16)p[2 * i];
            t.h[1] = (_Float16)p[2 * i + 1];
            u[i] = t.w;
        }
        unsigned t0 = hi ? u[0] : u[2];
        unsigned t1 = hi ? u[1] : u[3];
        unsigned t2 = hi ? u[4] : u[6];
        unsigned t3 = hi ? u[5] : u[7];
        const unsigned r0 = __shfl_xor(t0, 32);
        const unsigned r1 = __shfl_xor(t1, 32);
        const unsigned r2 = __shfl_xor(t2, 32);
        const unsigned r3 = __shfl_xor(t3, 32);
        Frag16 pf0, pf1;
        pf0.u[0] = hi ? r0 : u[0];
        pf0.u[1] = hi ? r1 : u[1];
        pf0.u[2] = hi ? u[2] : r0;
        pf0.u[3] = hi ? u[3] : r1;
        pf1.u[0] = hi ? r2 : u[4];
        pf1.u[1] = hi ? r3 : u[5];
        pf1.u[2] = hi ? u[6] : r2;
        pf1.u[3] = hi ? u[7] : r3;

        o0 = __builtin_amdgcn_mfma_f32_32x32x16_f16(vf00.v, pf0.v, o0, 0, 0, 0);
        o0 = __builtin_amdgcn_mfma_f32_32x32x16_f16(vf01.v, pf1.v, o0, 0, 0, 0);
        o1 = __builtin_amdgcn_mfma_f32_32x32x16_f16(vf10.v, pf0.v, o1, 0, 0, 0);
        o1 = __builtin_amdgcn_mfma_f32_32x32x16_f16(vf11.v, pf1.v, o1, 0, 0, 0);
    }

    const float inv = 1.f / lsum;
    const int b_ = bh >> 4, h_ = bh & 15;
    unsigned short* outp = O16 + ((size_t)(b_ * kL + q)) * kD + h_ * kHD;
#pragma unroll
    for (int g = 0; g < 4; ++g) {
        const int d = g * 8 + hi * 4;
        ushort4 w0, w1;
        w0.x = f2h(o0[4 * g + 0] * inv); w0.y = f2h(o0[4 * g + 1] * inv);
        w0.z = f2h(o0[4 * g + 2] * inv); w0.w = f2h(o0[4 * g + 3] * inv);
        w1.x = f2h(o1[4 * g + 0] * inv); w1.y = f2h(o1[4 * g + 1] * inv);
        w1.z = f2h(o1[4 * g + 2] * inv); w1.w = f2h(o1[4 * g + 3] * inv);
        *(ushort4*)(outp + d) = w0;
        *(ushort4*)(outp + 32 + d) = w1;
    }
}

// ---------------------------------------------------------------------------
extern "C" void kernel_launch(void* const* d_in, const int* in_sizes, int n_in,
                              void* d_out, int out_size, void* d_ws, size_t ws_size,
                              hipStream_t stream)
{
    const float* q  = (const float*)d_in[0];
    const float* k  = (const float*)d_in[1];
    const float* v  = (const float*)d_in[2];
    const float* Wq = (const float*)d_in[3];
    const float* bq = (const float*)d_in[4];
    const float* Wk = (const float*)d_in[5];
    const float* bk = (const float*)d_in[6];
    const float* Wv = (const float*)d_in[7];
    const float* bv = (const float*)d_in[8];
    const float* Wo = (const float*)d_in[9];
    const float* bo = (const float*)d_in[10];
    float* out = (float*)d_out;

    const size_t MD = (size_t)kM * kD;   // 4M elements
    const size_t DD = (size_t)kD * kD;   // 1M elements
    // ws (fp16 halfwords): A16 q|k|v (3*MD) | Wt q|k|v|o (4*DD) | Qh | Kh | Vt (3*MD/... heads=MD each)
    unsigned short* A16 = (unsigned short*)d_ws;          // 3 * MD
    unsigned short* Wt16 = A16 + 3 * MD;                  // 4 * DD
    unsigned short* Qh16 = Wt16 + 4 * DD;                 // MD
    unsigned short* Kh16 = Qh16 + MD;                     // MD
    unsigned short* Vt16 = Kh16 + MD;                     // MD
    unsigned short* O16  = A16;                           // reuse q-cast buffer

    const dim3 blk(256);

    hipLaunchKernelGGL(cast_f16_kernel, dim3(kM * kD / (256 * 8), 3), blk, 0, stream,
                       q, k, v, A16);
    hipLaunchKernelGGL(tcast_kernel, dim3(16, 16, 4), blk, 0, stream,
                       Wq, Wk, Wv, Wo, Wt16);

    hipLaunchKernelGGL((gemm16_kernel<1>), dim3(256), blk, 0, stream,
                       A16, Wt16, bq, (void*)Qh16);
    hipLaunchKernelGGL((gemm16_kernel<1>), dim3(256), blk, 0, stream,
                       A16 + MD, Wt16 + DD, bk, (void*)Kh16);
    hipLaunchKernelGGL((gemm16_kernel<2>), dim3(256), blk, 0, stream,
                       A16 + 2 * MD, Wt16 + 2 * DD, bv, (void*)Vt16);

    hipLaunchKernelGGL(attn_mfma_kernel, dim3(kL / 128, kB * kH), blk, 0, stream,
                       Qh16, Kh16, Vt16, O16);

    hipLaunchKernelGGL((gemm16_kernel<0>), dim3(256), blk, 0, stream,
                       O16, Wt16 + 3 * DD, bo, (void*)out);
}

// Round 4
// 147.540 us; speedup vs baseline: 9.1078x; 1.3221x over previous
//
#include <hip/hip_runtime.h>

namespace {
constexpr int kB  = 2;
constexpr int kL  = 2048;
constexpr int kD  = 1024;
constexpr int kH  = 16;
constexpr int kHD = 64;
constexpr int kM  = kB * kL;      // 4096 total rows
}

typedef _Float16 f16x8 __attribute__((ext_vector_type(8)));
typedef float    f32x16 __attribute__((ext_vector_type(16)));
typedef unsigned int u32;

union Frag16 { uint4 u4; unsigned u[4]; f16x8 v; };

__device__ __forceinline__ unsigned short f2h(float f) {
    return __builtin_bit_cast(unsigned short, (_Float16)f);
}

// async 16B global -> LDS (wave-uniform LDS base; HW adds lane*16)
__device__ __forceinline__ void gload16(const void* g, void* l) {
    __builtin_amdgcn_global_load_lds(
        (const __attribute__((address_space(1))) u32*)g,
        (__attribute__((address_space(3))) u32*)(unsigned long long)(__builtin_bit_cast(unsigned long long, l)),
        16, 0, 0);
}

// ---------------------------------------------------------------------------
// cast q,k,v (fp32, M x D) -> fp16, same layout. grid (2048, 3)
// ---------------------------------------------------------------------------
__global__ __launch_bounds__(256) void cast_f16_kernel(
    const float* __restrict__ q, const float* __restrict__ k,
    const float* __restrict__ v, unsigned short* __restrict__ dst)
{
    const float* src = blockIdx.y == 0 ? q : (blockIdx.y == 1 ? k : v);
    unsigned short* d = dst + (size_t)blockIdx.y * ((size_t)kM * kD);
    const size_t i = ((size_t)blockIdx.x * 256 + threadIdx.x) * 8;
    const float4 f0 = *(const float4*)(src + i);
    const float4 f1 = *(const float4*)(src + i + 4);
    _Float16 h[8];
    h[0] = (_Float16)f0.x; h[1] = (_Float16)f0.y;
    h[2] = (_Float16)f0.z; h[3] = (_Float16)f0.w;
    h[4] = (_Float16)f1.x; h[5] = (_Float16)f1.y;
    h[6] = (_Float16)f1.z; h[7] = (_Float16)f1.w;
    *(uint4*)(d + i) = *(uint4*)h;
}

// ---------------------------------------------------------------------------
// transpose-cast W (fp32 [k][n]) -> fp16 Wt [n][k]. grid (16, 16, 4)
// ---------------------------------------------------------------------------
__global__ __launch_bounds__(256) void tcast_kernel(
    const float* __restrict__ W0, const float* __restrict__ W1,
    const float* __restrict__ W2, const float* __restrict__ W3,
    unsigned short* __restrict__ WtBase)
{
    __shared__ _Float16 T[64][68];
    const float* W = blockIdx.z == 0 ? W0 : blockIdx.z == 1 ? W1
                   : blockIdx.z == 2 ? W2 : W3;
    unsigned short* Wt = WtBase + (size_t)blockIdx.z * ((size_t)kD * kD);
    const int k0 = blockIdx.y * 64, n0 = blockIdx.x * 64;
    const int tx = threadIdx.x & 15, ty = threadIdx.x >> 4;
#pragma unroll
    for (int i = 0; i < 4; ++i) {
        const int kk = i * 16 + ty;
        const float4 w = *(const float4*)&W[(size_t)(k0 + kk) * kD + n0 + tx * 4];
        T[tx * 4 + 0][kk] = (_Float16)w.x;
        T[tx * 4 + 1][kk] = (_Float16)w.y;
        T[tx * 4 + 2][kk] = (_Float16)w.z;
        T[tx * 4 + 3][kk] = (_Float16)w.w;
    }
    __syncthreads();
#pragma unroll
    for (int i = 0; i < 4; ++i) {
        const int nn = i * 16 + ty;
        *(ushort4*)&Wt[(size_t)(n0 + nn) * kD + k0 + tx * 4] = *(ushort4*)&T[nn][tx * 4];
    }
}

// ---------------------------------------------------------------------------
// fp16 MFMA GEMM + bias: C = A(M x 1024) @ W + bias, W given transposed [n][k].
// 128x128 tile, BK=64, 4 waves x (64x64), mfma_f32_32x32x16_f16.
// global_load_lds staging, pre-swizzled source + XOR-swizzled ds_read (T2).
// MODE 0: fp32 row-major; MODE 1: fp16 heads (B,H,L,HD); MODE 2: fp16 (B,H,HD,L)
// ---------------------------------------------------------------------------
template <int MODE>
__global__ __launch_bounds__(256) void gemm16_kernel(
    const unsigned short* __restrict__ A, const unsigned short* __restrict__ Wt,
    const float* __restrict__ bias, void* __restrict__ Cv)
{
    __shared__ unsigned short Als[2][128 * 64];
    __shared__ unsigned short Bls[2][128 * 64];

    const int tid = threadIdx.x;
    const int lane = tid & 63;
    const int wid = tid >> 6;
    const int l31 = lane & 31;
    const int hi = lane >> 5;
    const int by = blockIdx.x & 31;   // row-panel: same-A blocks share an XCD
    const int bx = blockIdx.x >> 5;
    const int row0 = by * 128;
    const int col0 = bx * 128;
    const int wr = wid >> 1, wc = wid & 1;

    const int rl = lane >> 3;         // row-in-group for staging
    const int sl = lane & 7;          // dest 16B slot
    const int ssrc = (sl ^ rl) * 8;   // swizzled source k-offset (elems)

    const unsigned short* Abase = A + (size_t)(row0 + wid * 32 + rl) * kD + ssrc;
    const unsigned short* Bbase = Wt + (size_t)(col0 + wid * 32 + rl) * kD + ssrc;

    f32x16 acc00{}, acc01{}, acc10{}, acc11{};

    auto stage = [&](int kt, int buf) {
#pragma unroll
        for (int i = 0; i < 4; ++i) {
            gload16(Abase + (size_t)(i * 8) * kD + kt * 64,
                    &Als[buf][(wid * 32 + i * 8) * 64]);
        }
#pragma unroll
        for (int i = 0; i < 4; ++i) {
            gload16(Bbase + (size_t)(i * 8) * kD + kt * 64,
                    &Bls[buf][(wid * 32 + i * 8) * 64]);
        }
    };

    const int ra0 = wr * 64 + l31;
    const int cb0 = wc * 64 + l31;

    stage(0, 0);
    int cur = 0;
    for (int kt = 0; kt < kD / 64; ++kt) {
        __syncthreads();
        if (kt + 1 < kD / 64) stage(kt + 1, cur ^ 1);
#pragma unroll
        for (int ks = 0; ks < 4; ++ks) {
            const int slot = (ks << 1) | hi;
            Frag16 a0, a1, b0, b1;
            a0.u4 = *(const uint4*)&Als[cur][ra0 * 64 + ((slot ^ (ra0 & 7)) << 3)];
            a1.u4 = *(const uint4*)&Als[cur][(ra0 + 32) * 64 + ((slot ^ ((ra0 + 32) & 7)) << 3)];
            b0.u4 = *(const uint4*)&Bls[cur][cb0 * 64 + ((slot ^ (cb0 & 7)) << 3)];
            b1.u4 = *(const uint4*)&Bls[cur][(cb0 + 32) * 64 + ((slot ^ ((cb0 + 32) & 7)) << 3)];
            acc00 = __builtin_amdgcn_mfma_f32_32x32x16_f16(a0.v, b0.v, acc00, 0, 0, 0);
            acc01 = __builtin_amdgcn_mfma_f32_32x32x16_f16(a0.v, b1.v, acc01, 0, 0, 0);
            acc10 = __builtin_amdgcn_mfma_f32_32x32x16_f16(a1.v, b0.v, acc10, 0, 0, 0);
            acc11 = __builtin_amdgcn_mfma_f32_32x32x16_f16(a1.v, b1.v, acc11, 0, 0, 0);
        }
        cur ^= 1;
    }

    // ---- epilogue ----
    const float bias0 = bias[col0 + wc * 64 + l31];
    const float bias1 = bias[col0 + wc * 64 + 32 + l31];

    const f32x16* accs[2][2] = {{&acc00, &acc01}, {&acc10, &acc11}};
#pragma unroll
    for (int rt = 0; rt < 2; ++rt) {
#pragma unroll
        for (int ct = 0; ct < 2; ++ct) {
            const f32x16& acv = *accs[rt][ct];
            const float bb = ct ? bias1 : bias0;
            const int c = col0 + wc * 64 + ct * 32 + l31;
            if (MODE == 2) {
                unsigned short* C = (unsigned short*)Cv;
#pragma unroll
                for (int qd = 0; qd < 4; ++qd) {
                    const int r = row0 + wr * 64 + rt * 32 + 8 * qd + 4 * hi;
                    const int b_ = r >> 11, l_ = r & (kL - 1);
                    ushort4 w;
                    w.x = f2h(acv[4 * qd + 0] + bb);
                    w.y = f2h(acv[4 * qd + 1] + bb);
                    w.z = f2h(acv[4 * qd + 2] + bb);
                    w.w = f2h(acv[4 * qd + 3] + bb);
                    *(ushort4*)&C[((size_t)(b_ * kH + (c >> 6)) * kHD + (c & 63)) * kL + l_] = w;
                }
            } else {
#pragma unroll
                for (int reg = 0; reg < 16; ++reg) {
                    const int r = row0 + wr * 64 + rt * 32 + (reg & 3) + 8 * (reg >> 2) + 4 * hi;
                    const float val = acv[reg] + bb;
                    if (MODE == 0) {
                        ((float*)Cv)[(size_t)r * kD + c] = val;
                    } else {
                        const int b_ = r >> 11, l_ = r & (kL - 1);
                        ((unsigned short*)Cv)[((size_t)(b_ * kH + (c >> 6)) * kL + l_) * kHD + (c & 63)] = f2h(val);
                    }
                }
            }
        }
    }
}

// ---------------------------------------------------------------------------
// MFMA flash attention, LDS-staged K/V (fp16 in, fp32 accum).
// Block = 4 waves x 32 q-rows = 128 rows. KVBLK=64, double-buffered LDS,
// global_load_lds staging (pre-swizzled source + XOR-swizzled ds_read).
// S^T = mfma(K, Q) (c0: keys 0..31, c1: keys 32..63 - independent chains);
// softmax lane-local; P^T built in-register; O^T = mfma(V^T, P^T).
// ---------------------------------------------------------------------------
__global__ __launch_bounds__(256) void attn_mfma_kernel(
    const unsigned short* __restrict__ Qh, const unsigned short* __restrict__ Kh,
    const unsigned short* __restrict__ Vt, unsigned short* __restrict__ O16)
{
    __shared__ unsigned short Kls[2][64 * 64];
    __shared__ unsigned short Vls[2][64 * 64];

    const int lane = threadIdx.x & 63;
    const int wid  = threadIdx.x >> 6;
    const int l31  = lane & 31;
    const int hi   = lane >> 5;
    const int qt = blockIdx.x, bh = blockIdx.y;
    const int q = qt * 128 + wid * 32 + l31;

    const size_t qkBase = (size_t)bh * kL * kHD;
    const unsigned short* Qp = Qh + qkBase + (size_t)q * kHD + hi * 8;
    Frag16 qf[4];
#pragma unroll
    for (int d = 0; d < 4; ++d) qf[d].u4 = *(const uint4*)(Qp + d * 16);

    // staging: lane covers (row = wid*16 + (lane>>3) [+8 for 2nd issue], slot = lane&7)
    const int srow = wid * 16 + (lane >> 3);
    const int sslot = lane & 7;
    const int soff = ((sslot ^ (srow & 7)) << 3);   // swizzled elem offset in row
    const unsigned short* Kg = Kh + qkBase + (size_t)srow * kHD + soff;
    const unsigned short* Vg = Vt + (size_t)bh * kHD * kL + (size_t)srow * kL + soff;

    auto stage = [&](int kt, int buf) {
        // K tile: keys kt*64.., rows = key index, row stride kHD
        gload16(Kg + (size_t)(kt * 64) * kHD,            &Kls[buf][(wid * 16) * 64]);
        gload16(Kg + (size_t)(kt * 64 + 8) * kHD,        &Kls[buf][(wid * 16 + 8) * 64]);
        // V tile: rows = hd, key offset kt*64 in column, row stride kL
        gload16(Vg + kt * 64,                            &Vls[buf][(wid * 16) * 64]);
        gload16(Vg + kt * 64 + (size_t)8 * kL,           &Vls[buf][(wid * 16 + 8) * 64]);
    };

    f32x16 o0{}, o1{};
    float m = -1e30f, lsum = 0.f;
    const float cexp = 0.125f * 1.44269504089f;

    stage(0, 0);
    int cur = 0;
    for (int kt = 0; kt < kL / 64; ++kt) {
        __syncthreads();                       // buf[cur] staged; prev reads done
        if (kt + 1 < kL / 64) stage(kt + 1, cur ^ 1);

        // ---- S^T = K @ Q^T (two independent 32-key chains)
        const int rA = l31, rB = l31 + 32;
        f32x16 c0{}, c1{};
        Frag16 kf0[4], kf1[4];
#pragma unroll
        for (int d = 0; d < 4; ++d) {
            const int s = (d << 1) | hi;
            kf0[d].u4 = *(const uint4*)&Kls[cur][rA * 64 + ((s ^ (rA & 7)) << 3)];
            kf1[d].u4 = *(const uint4*)&Kls[cur][rB * 64 + ((s ^ (rB & 7)) << 3)];
        }
        // V frags (independent of S -> overlap softmax)
        Frag16 vf0[4], vf1[4];
#pragma unroll
        for (int ks = 0; ks < 4; ++ks) {
            const int s = (ks << 1) | hi;
            vf0[ks].u4 = *(const uint4*)&Vls[cur][rA * 64 + ((s ^ (rA & 7)) << 3)];
            vf1[ks].u4 = *(const uint4*)&Vls[cur][rB * 64 + ((s ^ (rB & 7)) << 3)];
        }
        __builtin_amdgcn_s_setprio(1);
#pragma unroll
        for (int d = 0; d < 4; ++d) {
            c0 = __builtin_amdgcn_mfma_f32_32x32x16_f16(kf0[d].v, qf[d].v, c0, 0, 0, 0);
            c1 = __builtin_amdgcn_mfma_f32_32x32x16_f16(kf1[d].v, qf[d].v, c1, 0, 0, 0);
        }
        __builtin_amdgcn_s_setprio(0);

        // ---- online softmax over 64 new keys
        float mx = fmaxf(c0[0], c1[0]);
#pragma unroll
        for (int r = 1; r < 16; ++r) mx = fmaxf(mx, fmaxf(c0[r], c1[r]));
        mx = fmaxf(mx, __shfl_xor(mx, 32));
        if (mx > m + 48.f) {                   // defer-max
            const float corr = __builtin_amdgcn_exp2f((m - mx) * cexp);
            m = mx;
            lsum *= corr;
            o0 *= corr;
            o1 *= corr;
        }
        const float mc = m * cexp;
        float p0[16], p1[16];
        float rs = 0.f;
#pragma unroll
        for (int r = 0; r < 16; ++r) {
            p0[r] = __builtin_amdgcn_exp2f(fmaf(c0[r], cexp, -mc));
            p1[r] = __builtin_amdgcn_exp2f(fmaf(c1[r], cexp, -mc));
            rs += p0[r] + p1[r];
        }
        rs += __shfl_xor(rs, 32);
        lsum += rs;

        // ---- pack P -> fp16, build 4 P^T B-frags via partner exchanges
        unsigned u0[8], u1[8];
#pragma unroll
        for (int i = 0; i < 8; ++i) {
            union { _Float16 h[2]; unsigned w; } t;
            t.h[0] = (_Float16)p0[2 * i]; t.h[1] = (_Float16)p0[2 * i + 1];
            u0[i] = t.w;
            t.h[0] = (_Float16)p1[2 * i]; t.h[1] = (_Float16)p1[2 * i + 1];
            u1[i] = t.w;
        }
        Frag16 pf[4];
        {
            unsigned t0 = hi ? u0[0] : u0[2];
            unsigned t1 = hi ? u0[1] : u0[3];
            unsigned t2 = hi ? u0[4] : u0[6];
            unsigned t3 = hi ? u0[5] : u0[7];
            const unsigned r0 = __shfl_xor(t0, 32);
            const unsigned r1 = __shfl_xor(t1, 32);
            const unsigned r2 = __shfl_xor(t2, 32);
            const unsigned r3 = __shfl_xor(t3, 32);
            pf[0].u[0] = hi ? r0 : u0[0];
            pf[0].u[1] = hi ? r1 : u0[1];
            pf[0].u[2] = hi ? u0[2] : r0;
            pf[0].u[3] = hi ? u0[3] : r1;
            pf[1].u[0] = hi ? r2 : u0[4];
            pf[1].u[1] = hi ? r3 : u0[5];
            pf[1].u[2] = hi ? u0[6] : r2;
            pf[1].u[3] = hi ? u0[7] : r3;
        }
        {
            unsigned t0 = hi ? u1[0] : u1[2];
            unsigned t1 = hi ? u1[1] : u1[3];
            unsigned t2 = hi ? u1[4] : u1[6];
            unsigned t3 = hi ? u1[5] : u1[7];
            const unsigned r0 = __shfl_xor(t0, 32);
            const unsigned r1 = __shfl_xor(t1, 32);
            const unsigned r2 = __shfl_xor(t2, 32);
            const unsigned r3 = __shfl_xor(t3, 32);
            pf[2].u[0] = hi ? r0 : u1[0];
            pf[2].u[1] = hi ? r1 : u1[1];
            pf[2].u[2] = hi ? u1[2] : r0;
            pf[2].u[3] = hi ? u1[3] : r1;
            pf[3].u[0] = hi ? r2 : u1[4];
            pf[3].u[1] = hi ? r3 : u1[5];
            pf[3].u[2] = hi ? u1[6] : r2;
            pf[3].u[3] = hi ? u1[7] : r3;
        }

        // ---- O^T += V^T @ P^T
        __builtin_amdgcn_s_setprio(1);
#pragma unroll
        for (int ks = 0; ks < 4; ++ks) {
            o0 = __builtin_amdgcn_mfma_f32_32x32x16_f16(vf0[ks].v, pf[ks].v, o0, 0, 0, 0);
            o1 = __builtin_amdgcn_mfma_f32_32x32x16_f16(vf1[ks].v, pf[ks].v, o1, 0, 0, 0);
        }
        __builtin_amdgcn_s_setprio(0);
        cur ^= 1;
    }

    // ---- epilogue: normalize, write fp16 (B, L, D)
    const float inv = 1.f / lsum;
    const int b_ = bh >> 4, h_ = bh & 15;
    unsigned short* outp = O16 + ((size_t)(b_ * kL + q)) * kD + h_ * kHD;
#pragma unroll
    for (int g = 0; g < 4; ++g) {
        const int d = g * 8 + hi * 4;
        ushort4 w0, w1;
        w0.x = f2h(o0[4 * g + 0] * inv); w0.y = f2h(o0[4 * g + 1] * inv);
        w0.z = f2h(o0[4 * g + 2] * inv); w0.w = f2h(o0[4 * g + 3] * inv);
        w1.x = f2h(o1[4 * g + 0] * inv); w1.y = f2h(o1[4 * g + 1] * inv);
        w1.z = f2h(o1[4 * g + 2] * inv); w1.w = f2h(o1[4 * g + 3] * inv);
        *(ushort4*)(outp + d) = w0;
        *(ushort4*)(outp + 32 + d) = w1;
    }
}

// ---------------------------------------------------------------------------
extern "C" void kernel_launch(void* const* d_in, const int* in_sizes, int n_in,
                              void* d_out, int out_size, void* d_ws, size_t ws_size,
                              hipStream_t stream)
{
    const float* q  = (const float*)d_in[0];
    const float* k  = (const float*)d_in[1];
    const float* v  = (const float*)d_in[2];
    const float* Wq = (const float*)d_in[3];
    const float* bq = (const float*)d_in[4];
    const float* Wk = (const float*)d_in[5];
    const float* bk = (const float*)d_in[6];
    const float* Wv = (const float*)d_in[7];
    const float* bv = (const float*)d_in[8];
    const float* Wo = (const float*)d_in[9];
    const float* bo = (const float*)d_in[10];
    float* out = (float*)d_out;

    const size_t MD = (size_t)kM * kD;
    const size_t DD = (size_t)kD * kD;
    unsigned short* A16 = (unsigned short*)d_ws;          // 3 * MD
    unsigned short* Wt16 = A16 + 3 * MD;                  // 4 * DD
    unsigned short* Qh16 = Wt16 + 4 * DD;                 // MD
    unsigned short* Kh16 = Qh16 + MD;                     // MD
    unsigned short* Vt16 = Kh16 + MD;                     // MD
    unsigned short* O16  = A16;                           // reuse q-cast buffer

    const dim3 blk(256);

    hipLaunchKernelGGL(cast_f16_kernel, dim3(kM * kD / (256 * 8), 3), blk, 0, stream,
                       q, k, v, A16);
    hipLaunchKernelGGL(tcast_kernel, dim3(16, 16, 4), blk, 0, stream,
                       Wq, Wk, Wv, Wo, Wt16);

    hipLaunchKernelGGL((gemm16_kernel<1>), dim3(256), blk, 0, stream,
                       A16, Wt16, bq, (void*)Qh16);
    hipLaunchKernelGGL((gemm16_kernel<1>), dim3(256), blk, 0, stream,
                       A16 + MD, Wt16 + DD, bk, (void*)Kh16);
    hipLaunchKernelGGL((gemm16_kernel<2>), dim3(256), blk, 0, stream,
                       A16 + 2 * MD, Wt16 + 2 * DD, bv, (void*)Vt16);

    hipLaunchKernelGGL(attn_mfma_kernel, dim3(kL / 128, kB * kH), blk, 0, stream,
                       Qh16, Kh16, Vt16, O16);

    hipLaunchKernelGGL((gemm16_kernel<0>), dim3(256), blk, 0, stream,
                       O16, Wt16 + 3 * DD, bo, (void*)out);
}